// Round 1
// baseline (905.612 us; speedup 1.0000x reference)
//
#include <hip/hip_runtime.h>
#include <math.h>

// RandomLowRes2D: per-image Gaussian blur (R=15, symmetric pad) + linear
// down/up resample along axis chosen per-image at runtime.
//
// Fusion notes:
//  - low[j] = (1-fr)*s[la] + fr*s[la+1] collapses blur+downsample into ONE
//    32-tap filter on img: cw[k] = (1-fr)*w[k] + fr*w[k-1]  (w[-1]=w[31]=0).
//  - res >= 1  =>  lo2_i(i) non-decreasing, step <= 1  =>  upsample streams
//    with two live low values per thread. No workspace needed.
//  - axis==0 vs axis==1 is just a stride swap (su,sv); control flow stays
//    block-uniform (one image per block).

#define HH 512
#define RR 15
#define TAPS 31
#define SEG 64            // output rows per segment
#define NSEG (HH / SEG)

#define SIG_PER_FWHM 0.42466090014400953f  // 1/sqrt(8 ln 2)

__global__ __launch_bounds__(256) void lowres2d_kernel(
    const float* __restrict__ x,
    const float* __restrict__ resolution,
    const int*   __restrict__ axis,
    const float* __restrict__ gap,
    float* __restrict__ out)
{
    const int tid = threadIdx.x;
    const int n   = blockIdx.z;                  // image index
    const int seg = blockIdx.y;                  // output-row segment
    const int v   = blockIdx.x * 256 + tid;      // coord along non-degraded axis

    const float res = resolution[n];
    const int   ax  = axis[n];
    const float gp  = gap[n];
    const float sig = fmaxf(res * gp * SIG_PER_FWHM, 1e-6f);

    int n_low = (int)floorf(512.0f / res);
    if (n_low < 1) n_low = 1;
    const float nlm1f = (float)(n_low - 1);

    // we[0] = 0, we[1..31] = normalized gaussian, we[32] = 0  (guard zeros so
    // the combined 32-tap weight cw[k] = (1-fr)*we[k+1] + fr*we[k] is uniform)
    __shared__ float we[TAPS + 2];
    if (tid == 0) {
        we[0] = 0.0f;
        we[TAPS + 1] = 0.0f;
        float tot = 0.0f;
        for (int k = 0; k < TAPS; ++k) {
            float d = (float)(k - RR) / sig;
            float r = expf(-0.5f * d * d);
            we[k + 1] = r;
            tot += r;
        }
        for (int k = 0; k < TAPS; ++k) we[k + 1] /= tot;
    }
    __syncthreads();

    const size_t base = (size_t)n * (512 * 512);
    const int su = (ax == 0) ? 512 : 1;   // stride along degraded axis
    const int sv = (ax == 0) ? 1 : 512;   // stride along parallel axis
    const float* img = x + base;
    float* o = out + base;
    const int voff = v * sv;

    // low[j] = 32-tap fused blur+downsample filter at low-res row j
    auto compute_low = [&](int j) -> float {
        float pos = fminf((float)j * res, 511.0f);
        float lof = floorf(pos);
        float fr  = pos - lof;
        int   la  = (int)lof;
        float omf = 1.0f - fr;
        float acc = 0.0f;
        #pragma unroll
        for (int k = 0; k < 32; ++k) {
            int t = la - RR + k;                 // in [-15, 527]
            t = (t < 0)   ? (-1 - t)   : t;      // symmetric reflect (single)
            t = (t > 511) ? (1023 - t) : t;
            float cw = omf * we[k + 1] + fr * we[k];
            acc += cw * img[(size_t)(t * su + voff)];
        }
        return acc;
    };

    const int i0 = seg * SEG;

    // initialize the two live low values for this segment's first output row
    float p0 = fminf((float)i0 / res, nlm1f);
    int j = (int)floorf(p0);
    if (j > n_low - 1) j = n_low - 1;
    float lowA = compute_low(j);
    int jB = (j + 1 < n_low) ? (j + 1) : (n_low - 1);
    float lowB = (jB == j) ? lowA : compute_low(jB);

    for (int i = i0; i < i0 + SEG; ++i) {
        float pos2 = fminf((float)i / res, nlm1f);   // exact IEEE div: floor
        float l2f  = floorf(pos2);                   // decisions match XLA
        float fr2  = pos2 - l2f;
        int lo2 = (int)l2f;
        if (lo2 > n_low - 1) lo2 = n_low - 1;

        if (lo2 == j + 1) {                          // common streaming step
            j = lo2;
            lowA = lowB;
            jB = (j + 1 < n_low) ? (j + 1) : (n_low - 1);
            lowB = (jB == j) ? lowA : compute_low(jB);
        } else if (lo2 > j + 1) {                    // defensive (res<1 never
            j = lo2;                                 // happens, but be safe)
            lowA = compute_low(j);
            jB = (j + 1 < n_low) ? (j + 1) : (n_low - 1);
            lowB = (jB == j) ? lowA : compute_low(jB);
        }

        o[(size_t)(i * su + voff)] = lowA * (1.0f - fr2) + lowB * fr2;
    }
}

extern "C" void kernel_launch(void* const* d_in, const int* in_sizes, int n_in,
                              void* d_out, int out_size, void* d_ws, size_t ws_size,
                              hipStream_t stream) {
    const float* x          = (const float*)d_in[0];
    const float* resolution = (const float*)d_in[1];
    const int*   axis       = (const int*)d_in[2];
    const float* gap        = (const float*)d_in[3];
    float* out = (float*)d_out;

    const int n_img = in_sizes[1];   // B*C = 64

    dim3 grid(2, NSEG, n_img);       // (half of parallel axis, segment, image)
    lowres2d_kernel<<<grid, 256, 0, stream>>>(x, resolution, axis, gap, out);
}

// Round 2
// 245.537 us; speedup vs baseline: 3.6883x; 3.6883x over previous
//
#include <hip/hip_runtime.h>
#include <math.h>

// RandomLowRes2D: per-image Gaussian blur (R=15, symmetric pad) + linear
// down/up resample along a per-image runtime axis.
//
// Fusion: low[j] = (1-fr)*s[la] + fr*s[la+1] collapses blur+downsample into a
// single 32-tap filter on img: cw[k] = (1-fr)*w[k] + fr*w[k-1] (w[-1]=w[31]=0).
//
// Coalescing strategy (Round 2 — ax1 scatter was the Round-1 bottleneck):
//   ax==0: degraded axis = H, lanes along contiguous W -> already coalesced.
//          Streaming two-live-lows per thread, SEG0=32 rows/block.
//   ax==1: degraded axis = W (contiguous). Per block: stage 8 rows x 512 cols
//          in LDS (float4 coalesced), compute lows j-parallel into LDS,
//          upsample from LDS, float4 coalesced stores. No global transpose.

#define RR 15
#define TAPS 31
#define SEG0 32                  // ax0: output rows per block
#define SIG_PER_FWHM 0.42466090014400953f  // 1/sqrt(8 ln 2)

__global__ __launch_bounds__(256) void lowres2d_kernel(
    const float* __restrict__ x,
    const float* __restrict__ resolution,
    const int*   __restrict__ axis,
    const float* __restrict__ gap,
    float* __restrict__ out)
{
    const int tid = threadIdx.x;
    const int n   = blockIdx.y;          // image index
    const int bx  = blockIdx.x;          // 0..63

    const float res = resolution[n];
    const int   ax  = axis[n];
    const float gp  = gap[n];

    // ax0 images only use 32 blocks (SEG0=32 -> 16 segs x 2 v-halves)
    if (ax == 0 && bx >= 32) return;

    const float sig = fmaxf(res * gp * SIG_PER_FWHM, 1e-6f);
    int n_low = (int)floorf(512.0f / res);
    if (n_low < 1) n_low = 1;
    if (n_low > 512) n_low = 512;
    const float nlm1f = (float)(n_low - 1);

    // we[0] = 0, we[1..31] = normalized gaussian, we[32] = 0 (guard zeros so
    // cw[k] = (1-fr)*we[k+1] + fr*we[k] is branch-free over k)
    __shared__ float we[TAPS + 2];
    __shared__ float s_img[8][520];      // ax1: input tile (pad 520 vs banks)
    __shared__ float s_low[8][516];      // ax1: low-res intermediate

    if (tid == 0) {
        we[0] = 0.0f;
        we[TAPS + 1] = 0.0f;
        float tot = 0.0f;
        for (int k = 0; k < TAPS; ++k) {
            float d = (float)(k - RR) / sig;
            float r = expf(-0.5f * d * d);
            we[k + 1] = r;
            tot += r;
        }
        for (int k = 0; k < TAPS; ++k) we[k + 1] /= tot;
    }
    __syncthreads();

    const size_t base = (size_t)n * (512 * 512);
    const float* img = x + base;
    float* o = out + base;

    if (ax == 0) {
        // ---------------- ax0: streaming, fully coalesced ----------------
        const int v   = (bx & 1) * 256 + tid;    // column (contiguous axis)
        const int seg = bx >> 1;                 // 16 segments of SEG0 rows
        const int i0  = seg * SEG0;

        auto compute_low = [&](int j) -> float {
            float pos = fminf((float)j * res, 511.0f);
            float lof = floorf(pos);
            float fr  = pos - lof;
            int   la  = (int)lof;
            float omf = 1.0f - fr;
            float acc = 0.0f;
            #pragma unroll
            for (int k = 0; k < 32; ++k) {
                int t = la - RR + k;                 // in [-15, 527]
                t = (t < 0)   ? (-1 - t)   : t;      // symmetric reflect
                t = (t > 511) ? (1023 - t) : t;
                float cw = omf * we[k + 1] + fr * we[k];
                acc += cw * img[(size_t)(t * 512 + v)];
            }
            return acc;
        };

        float p0 = fminf((float)i0 / res, nlm1f);
        int j = (int)floorf(p0);
        if (j > n_low - 1) j = n_low - 1;
        float lowA = compute_low(j);
        int jB = (j + 1 < n_low) ? (j + 1) : (n_low - 1);
        float lowB = (jB == j) ? lowA : compute_low(jB);

        for (int i = i0; i < i0 + SEG0; ++i) {
            float pos2 = fminf((float)i / res, nlm1f);  // exact IEEE div
            float l2f  = floorf(pos2);
            float fr2  = pos2 - l2f;
            int lo2 = (int)l2f;
            if (lo2 > n_low - 1) lo2 = n_low - 1;

            if (lo2 == j + 1) {
                j = lo2;
                lowA = lowB;
                jB = (j + 1 < n_low) ? (j + 1) : (n_low - 1);
                lowB = (jB == j) ? lowA : compute_low(jB);
            } else if (lo2 > j + 1) {
                j = lo2;
                lowA = compute_low(j);
                jB = (j + 1 < n_low) ? (j + 1) : (n_low - 1);
                lowB = (jB == j) ? lowA : compute_low(jB);
            }
            o[(size_t)(i * 512 + v)] = lowA * (1.0f - fr2) + lowB * fr2;
        }
    } else {
        // ---------------- ax1: LDS-tiled, coalesced load/store -----------
        const int h0 = bx * 8;                   // 8 rows per block

        // load 8x512 tile, float4 coalesced
        const float4* img4 = (const float4*)(img + (size_t)h0 * 512);
        #pragma unroll
        for (int p = 0; p < 4; ++p) {
            int m = p * 256 + tid;
            int r = m >> 7, c4 = m & 127;
            float4 val = img4[r * 128 + c4];
            s_img[r][c4 * 4 + 0] = val.x;
            s_img[r][c4 * 4 + 1] = val.y;
            s_img[r][c4 * 4 + 2] = val.z;
            s_img[r][c4 * 4 + 3] = val.w;
        }
        __syncthreads();

        // compute lows: j-parallel (32 threads per row-group), no dep chain
        {
            const int r = tid >> 5;
            for (int j = (tid & 31); j < n_low; j += 32) {
                float pos = fminf((float)j * res, 511.0f);
                float lof = floorf(pos);
                float fr  = pos - lof;
                int   la  = (int)lof;
                float omf = 1.0f - fr;
                float acc = 0.0f;
                #pragma unroll
                for (int k = 0; k < 32; ++k) {
                    int t = la - RR + k;
                    t = (t < 0)   ? (-1 - t)   : t;
                    t = (t > 511) ? (1023 - t) : t;
                    float cw = omf * we[k + 1] + fr * we[k];
                    acc += cw * s_img[r][t];
                }
                s_low[r][j] = acc;
            }
        }
        __syncthreads();

        // upsample + coalesced float4 stores
        float4* out4 = (float4*)(o + (size_t)h0 * 512);
        #pragma unroll
        for (int p = 0; p < 4; ++p) {
            int m = p * 256 + tid;
            int r = m >> 7, c4 = m & 127;
            float4 ov;
            float vals[4];
            #pragma unroll
            for (int q = 0; q < 4; ++q) {
                int i = c4 * 4 + q;
                float pos2 = fminf((float)i / res, nlm1f);
                float l2f  = floorf(pos2);
                float fr2  = pos2 - l2f;
                int lo2 = (int)l2f;
                if (lo2 > n_low - 1) lo2 = n_low - 1;
                int hi2 = (lo2 + 1 < n_low) ? (lo2 + 1) : (n_low - 1);
                vals[q] = s_low[r][lo2] * (1.0f - fr2) + s_low[r][hi2] * fr2;
            }
            ov.x = vals[0]; ov.y = vals[1]; ov.z = vals[2]; ov.w = vals[3];
            out4[r * 128 + c4] = ov;
        }
    }
}

extern "C" void kernel_launch(void* const* d_in, const int* in_sizes, int n_in,
                              void* d_out, int out_size, void* d_ws, size_t ws_size,
                              hipStream_t stream) {
    const float* x          = (const float*)d_in[0];
    const float* resolution = (const float*)d_in[1];
    const int*   axis       = (const int*)d_in[2];
    const float* gap        = (const float*)d_in[3];
    float* out = (float*)d_out;

    const int n_img = in_sizes[1];   // B*C = 64

    dim3 grid(64, n_img);
    lowres2d_kernel<<<grid, 256, 0, stream>>>(x, resolution, axis, gap, out);
}

// Round 3
// 166.219 us; speedup vs baseline: 5.4483x; 1.4772x over previous
//
#include <hip/hip_runtime.h>
#include <math.h>

// RandomLowRes2D: per-image Gaussian blur (R=15, symmetric pad) + linear
// down/up resample along a per-image runtime axis.
//
// Fusion: low[j] = (1-fr)*s[la] + fr*s[la+1] collapses blur+downsample into a
// single fused filter on img: cw[k] = (1-fr)*we[k+1] + fr*we[k].
//
// Round 3:
//  - adaptive tap radius kr = min(15, floor(5.2565*sigma)+1): raw gaussian
//    < 1e-6 outside +-kr and the normalization sum is >= 1 (center tap = 1),
//    so dropped normalized weights < 1e-6 each -> error << 0.108 threshold.
//    Fused window k in [15-kr, 16+kr] (2kr+2 taps, median ~10 vs fixed 32).
//  - reflect clamps hoisted: interior la (la>=kr && la<=510-kr) skips them.
//  - occupancy: ax1 tile 8->4 rows (LDS 33->16.7 KB), no 32x unroll.
//  - ax0: float2 per thread (512 cols per 256-thread block), SEG0=16.

#define RR 15
#define TAPS 31
#define SEG0 16                  // ax0: output rows per block (32 blocks/img)
#define SIG_PER_FWHM 0.42466090014400953f  // 1/sqrt(8 ln 2)

__global__ __launch_bounds__(256) void lowres2d_kernel(
    const float* __restrict__ x,
    const float* __restrict__ resolution,
    const int*   __restrict__ axis,
    const float* __restrict__ gap,
    float* __restrict__ out)
{
    const int tid = threadIdx.x;
    const int n   = blockIdx.y;          // image index
    const int bx  = blockIdx.x;          // 0..127

    const float res = resolution[n];
    const int   ax  = axis[n];
    const float gp  = gap[n];

    // ax0 images use 32 blocks of SEG0=16 rows; rest exit (block-uniform)
    if (ax == 0 && bx >= 32) return;

    const float sig = fmaxf(res * gp * SIG_PER_FWHM, 1e-6f);
    int n_low = (int)floorf(512.0f / res);
    if (n_low < 1) n_low = 1;
    if (n_low > 512) n_low = 512;
    const float nlm1f = (float)(n_low - 1);

    // adaptive radius: exp(-0.5 (k/sig)^2) < 1e-6  <=>  k > 5.2565*sig
    int kr = (int)(sig * 5.2565f) + 1;
    if (kr > RR) kr = RR;
    const int k0 = RR - kr, k1 = RR + 1 + kr;   // fused window k in [k0, k1]
    const int la_lo = kr, la_hi = 510 - kr;     // interior: no reflect needed

    // we[0]=0, we[1..31]=normalized gaussian, we[32]=0 (guards for fused cw)
    __shared__ float we[TAPS + 2];
    __shared__ float s_img[4][520];      // ax1: input tile
    __shared__ float s_low[4][516];      // ax1: low-res intermediate

    if (tid == 0) {
        we[0] = 0.0f;
        we[TAPS + 1] = 0.0f;
        float tot = 0.0f;
        for (int k = 0; k < TAPS; ++k) {
            float d = (float)(k - RR) / sig;
            float r = expf(-0.5f * d * d);
            we[k + 1] = r;
            tot += r;
        }
        for (int k = 0; k < TAPS; ++k) we[k + 1] /= tot;
    }
    __syncthreads();

    const size_t base = (size_t)n * (512 * 512);
    const float* img = x + base;
    float* o = out + base;

    if (ax == 0) {
        // ---------------- ax0: streaming, coalesced, float2/thread --------
        const int v2  = tid;             // column pair: cols 2*v2, 2*v2+1
        const int i0  = bx * SEG0;
        const float2* img2 = (const float2*)img;
        float2* out2 = (float2*)o;

        auto compute_low = [&](int j) -> float2 {
            float pos = fminf((float)j * res, 511.0f);
            float lof = floorf(pos);
            float fr  = pos - lof;
            int   la  = (int)lof;
            float omf = 1.0f - fr;
            float2 acc = make_float2(0.0f, 0.0f);
            if (la >= la_lo && la <= la_hi) {        // block-uniform branch
                for (int k = k0; k <= k1; ++k) {
                    int t = la - RR + k;
                    float cw = omf * we[k + 1] + fr * we[k];
                    float2 val = img2[(size_t)(t * 256 + v2)];
                    acc.x += cw * val.x;
                    acc.y += cw * val.y;
                }
            } else {
                for (int k = k0; k <= k1; ++k) {
                    int t = la - RR + k;
                    t = (t < 0)   ? (-1 - t)   : t;  // symmetric reflect
                    t = (t > 511) ? (1023 - t) : t;
                    float cw = omf * we[k + 1] + fr * we[k];
                    float2 val = img2[(size_t)(t * 256 + v2)];
                    acc.x += cw * val.x;
                    acc.y += cw * val.y;
                }
            }
            return acc;
        };

        float p0 = fminf((float)i0 / res, nlm1f);
        int j = (int)floorf(p0);
        if (j > n_low - 1) j = n_low - 1;
        float2 lowA = compute_low(j);
        int jB = (j + 1 < n_low) ? (j + 1) : (n_low - 1);
        float2 lowB = (jB == j) ? lowA : compute_low(jB);

        for (int i = i0; i < i0 + SEG0; ++i) {
            float pos2 = fminf((float)i / res, nlm1f);  // exact IEEE div
            float l2f  = floorf(pos2);
            float fr2  = pos2 - l2f;
            int lo2 = (int)l2f;
            if (lo2 > n_low - 1) lo2 = n_low - 1;

            if (lo2 == j + 1) {
                j = lo2;
                lowA = lowB;
                jB = (j + 1 < n_low) ? (j + 1) : (n_low - 1);
                lowB = (jB == j) ? lowA : compute_low(jB);
            } else if (lo2 > j + 1) {
                j = lo2;
                lowA = compute_low(j);
                jB = (j + 1 < n_low) ? (j + 1) : (n_low - 1);
                lowB = (jB == j) ? lowA : compute_low(jB);
            }
            float omf2 = 1.0f - fr2;
            out2[(size_t)(i * 256 + v2)] =
                make_float2(lowA.x * omf2 + lowB.x * fr2,
                            lowA.y * omf2 + lowB.y * fr2);
        }
    } else {
        // ---------------- ax1: LDS-tiled 4 rows, coalesced ----------------
        const int h0 = bx * 4;

        // load 4x512 tile, float4 coalesced (512 float4 over 256 threads)
        const float4* img4 = (const float4*)(img + (size_t)h0 * 512);
        #pragma unroll
        for (int p = 0; p < 2; ++p) {
            int m = p * 256 + tid;
            int r = m >> 7, c4 = m & 127;
            ((float4*)&s_img[r][0])[c4] = img4[r * 128 + c4];
        }
        __syncthreads();

        // compute lows: one wave per row (r uniform per wave), j strided 64
        {
            const int r = tid >> 6;
            for (int j = (tid & 63); j < n_low; j += 64) {
                float pos = fminf((float)j * res, 511.0f);
                float lof = floorf(pos);
                float fr  = pos - lof;
                int   la  = (int)lof;
                float omf = 1.0f - fr;
                float acc = 0.0f;
                if (la >= la_lo && la <= la_hi) {
                    for (int k = k0; k <= k1; ++k) {
                        int t = la - RR + k;
                        float cw = omf * we[k + 1] + fr * we[k];
                        acc += cw * s_img[r][t];
                    }
                } else {
                    for (int k = k0; k <= k1; ++k) {
                        int t = la - RR + k;
                        t = (t < 0)   ? (-1 - t)   : t;
                        t = (t > 511) ? (1023 - t) : t;
                        float cw = omf * we[k + 1] + fr * we[k];
                        acc += cw * s_img[r][t];
                    }
                }
                s_low[r][j] = acc;
            }
        }
        __syncthreads();

        // upsample + coalesced float4 stores
        float4* out4 = (float4*)(o + (size_t)h0 * 512);
        #pragma unroll
        for (int p = 0; p < 2; ++p) {
            int m = p * 256 + tid;
            int r = m >> 7, c4 = m & 127;
            float vals[4];
            #pragma unroll
            for (int q = 0; q < 4; ++q) {
                int i = c4 * 4 + q;
                float pos2 = fminf((float)i / res, nlm1f);
                float l2f  = floorf(pos2);
                float fr2  = pos2 - l2f;
                int lo2 = (int)l2f;
                if (lo2 > n_low - 1) lo2 = n_low - 1;
                int hi2 = (lo2 + 1 < n_low) ? (lo2 + 1) : (n_low - 1);
                vals[q] = s_low[r][lo2] * (1.0f - fr2) + s_low[r][hi2] * fr2;
            }
            float4 ov;
            ov.x = vals[0]; ov.y = vals[1]; ov.z = vals[2]; ov.w = vals[3];
            out4[r * 128 + c4] = ov;
        }
    }
}

extern "C" void kernel_launch(void* const* d_in, const int* in_sizes, int n_in,
                              void* d_out, int out_size, void* d_ws, size_t ws_size,
                              hipStream_t stream) {
    const float* x          = (const float*)d_in[0];
    const float* resolution = (const float*)d_in[1];
    const int*   axis       = (const int*)d_in[2];
    const float* gap        = (const float*)d_in[3];
    float* out = (float*)d_out;

    const int n_img = in_sizes[1];   // B*C = 64

    dim3 grid(128, n_img);
    lowres2d_kernel<<<grid, 256, 0, stream>>>(x, resolution, axis, gap, out);
}

// Round 4
// 132.717 us; speedup vs baseline: 6.8236x; 1.2524x over previous
//
#include <hip/hip_runtime.h>
#include <math.h>

// RandomLowRes2D: per-image Gaussian blur (R=15, symmetric pad) + linear
// down/up resample along a per-image runtime axis.
//
// Fusion: low[j] = (1-fr)*s[la] + fr*s[la+1] collapses blur+downsample into a
// single fused filter on img: cw[k] = (1-fr)*we[k+1] + fr*we[k]
//                                   = fma(fr, dwe[k], we[k+1]),
// with dwe[k] = we[k] - we[k+1] precomputed.
//
// Round 4:
//  - weight init parallelized across lanes 0..31 of wave 0 (expf each,
//    __shfl_xor butterfly sum, __shfl_up for dwe) — Round-3 had thread 0
//    doing 31 serial expf while 3 waves waited at the barrier.
//  - dwe table: per-tap weight = 1 FMA (was mul+mul+add).
//  - #pragma unroll 4 on interior tap loops (VGPR 16 -> more loads in flight).
//  - ax0 SEG0 16->8 (64 blocks/image) for finer load balance.

#define RR 15
#define TAPS 31
#define SEG0 8                   // ax0: output rows per block (64 blocks/img)
#define SIG_PER_FWHM 0.42466090014400953f  // 1/sqrt(8 ln 2)

__global__ __launch_bounds__(256) void lowres2d_kernel(
    const float* __restrict__ x,
    const float* __restrict__ resolution,
    const int*   __restrict__ axis,
    const float* __restrict__ gap,
    float* __restrict__ out)
{
    const int tid = threadIdx.x;
    const int n   = blockIdx.y;          // image index
    const int bx  = blockIdx.x;          // 0..127

    const float res = resolution[n];
    const int   ax  = axis[n];
    const float gp  = gap[n];

    // ax0 images use 64 blocks of SEG0=8 rows; rest exit (block-uniform)
    if (ax == 0 && bx >= 64) return;

    const float sig = fmaxf(res * gp * SIG_PER_FWHM, 1e-6f);
    int n_low = (int)floorf(512.0f / res);
    if (n_low < 1) n_low = 1;
    if (n_low > 512) n_low = 512;
    const float nlm1f = (float)(n_low - 1);

    // adaptive radius: normalized weights < 1e-6 outside +-kr (sum >= 1)
    int kr = (int)(sig * 5.2565f) + 1;
    if (kr > RR) kr = RR;
    const int k0 = RR - kr, k1 = RR + 1 + kr;   // fused window k in [k0, k1]
    const int la_lo = kr, la_hi = 510 - kr;     // interior: no reflect needed

    // we[0]=0, we[1..31]=normalized gaussian, we[32]=0; dwe[k]=we[k]-we[k+1]
    __shared__ float we[34];
    __shared__ float dwe[32];
    __shared__ float s_img[4][520];      // ax1: input tile
    __shared__ float s_low[4][516];      // ax1: low-res intermediate

    if (tid < 32) {
        const int k = tid;
        float r = 0.0f;
        if (k < TAPS) {
            float d = (float)(k - RR) / sig;
            r = expf(-0.5f * d * d);
        }
        float tot = r;
        tot += __shfl_xor(tot, 1, 32);
        tot += __shfl_xor(tot, 2, 32);
        tot += __shfl_xor(tot, 4, 32);
        tot += __shfl_xor(tot, 8, 32);
        tot += __shfl_xor(tot, 16, 32);
        float rm1 = __shfl_up(r, 1, 32);
        if (k == 0) rm1 = 0.0f;
        const float inv = 1.0f / tot;            // tot >= 1 (center tap)
        we[k + 1] = r * inv;                     // lane31 writes we[32]=0
        if (k == 0) we[0] = 0.0f;
        dwe[k] = (rm1 - r) * inv;
    }
    __syncthreads();

    const size_t base = (size_t)n * (512 * 512);
    const float* img = x + base;
    float* o = out + base;

    if (ax == 0) {
        // ---------------- ax0: streaming, coalesced, float2/thread --------
        const int v2  = tid;             // column pair: cols 2*v2, 2*v2+1
        const int i0  = bx * SEG0;
        const float2* img2 = (const float2*)img;
        float2* out2 = (float2*)o;

        auto compute_low = [&](int j) -> float2 {
            float pos = fminf((float)j * res, 511.0f);
            float lof = floorf(pos);
            float fr  = pos - lof;
            int   la  = (int)lof;
            float2 acc = make_float2(0.0f, 0.0f);
            if (la >= la_lo && la <= la_hi) {        // block-uniform branch
                #pragma unroll 4
                for (int k = k0; k <= k1; ++k) {
                    int t = la - RR + k;
                    float cw = fmaf(fr, dwe[k], we[k + 1]);
                    float2 val = img2[(size_t)(t * 256 + v2)];
                    acc.x = fmaf(cw, val.x, acc.x);
                    acc.y = fmaf(cw, val.y, acc.y);
                }
            } else {
                for (int k = k0; k <= k1; ++k) {
                    int t = la - RR + k;
                    t = (t < 0)   ? (-1 - t)   : t;  // symmetric reflect
                    t = (t > 511) ? (1023 - t) : t;
                    float cw = fmaf(fr, dwe[k], we[k + 1]);
                    float2 val = img2[(size_t)(t * 256 + v2)];
                    acc.x = fmaf(cw, val.x, acc.x);
                    acc.y = fmaf(cw, val.y, acc.y);
                }
            }
            return acc;
        };

        float p0 = fminf((float)i0 / res, nlm1f);
        int j = (int)floorf(p0);
        if (j > n_low - 1) j = n_low - 1;
        float2 lowA = compute_low(j);
        int jB = (j + 1 < n_low) ? (j + 1) : (n_low - 1);
        float2 lowB = (jB == j) ? lowA : compute_low(jB);

        for (int i = i0; i < i0 + SEG0; ++i) {
            float pos2 = fminf((float)i / res, nlm1f);  // exact IEEE div
            float l2f  = floorf(pos2);
            float fr2  = pos2 - l2f;
            int lo2 = (int)l2f;
            if (lo2 > n_low - 1) lo2 = n_low - 1;

            if (lo2 == j + 1) {
                j = lo2;
                lowA = lowB;
                jB = (j + 1 < n_low) ? (j + 1) : (n_low - 1);
                lowB = (jB == j) ? lowA : compute_low(jB);
            } else if (lo2 > j + 1) {
                j = lo2;
                lowA = compute_low(j);
                jB = (j + 1 < n_low) ? (j + 1) : (n_low - 1);
                lowB = (jB == j) ? lowA : compute_low(jB);
            }
            float omf2 = 1.0f - fr2;
            out2[(size_t)(i * 256 + v2)] =
                make_float2(lowA.x * omf2 + lowB.x * fr2,
                            lowA.y * omf2 + lowB.y * fr2);
        }
    } else {
        // ---------------- ax1: LDS-tiled 4 rows, coalesced ----------------
        const int h0 = bx * 4;

        // load 4x512 tile, float4 coalesced (512 float4 over 256 threads)
        const float4* img4 = (const float4*)(img + (size_t)h0 * 512);
        #pragma unroll
        for (int p = 0; p < 2; ++p) {
            int m = p * 256 + tid;
            int r = m >> 7, c4 = m & 127;
            ((float4*)&s_img[r][0])[c4] = img4[r * 128 + c4];
        }
        __syncthreads();

        // compute lows: one wave per row (r uniform per wave), j strided 64
        {
            const int r = tid >> 6;
            for (int j = (tid & 63); j < n_low; j += 64) {
                float pos = fminf((float)j * res, 511.0f);
                float lof = floorf(pos);
                float fr  = pos - lof;
                int   la  = (int)lof;
                float acc = 0.0f;
                if (la >= la_lo && la <= la_hi) {
                    #pragma unroll 4
                    for (int k = k0; k <= k1; ++k) {
                        int t = la - RR + k;
                        float cw = fmaf(fr, dwe[k], we[k + 1]);
                        acc = fmaf(cw, s_img[r][t], acc);
                    }
                } else {
                    for (int k = k0; k <= k1; ++k) {
                        int t = la - RR + k;
                        t = (t < 0)   ? (-1 - t)   : t;
                        t = (t > 511) ? (1023 - t) : t;
                        float cw = fmaf(fr, dwe[k], we[k + 1]);
                        acc = fmaf(cw, s_img[r][t], acc);
                    }
                }
                s_low[r][j] = acc;
            }
        }
        __syncthreads();

        // upsample + coalesced float4 stores
        float4* out4 = (float4*)(o + (size_t)h0 * 512);
        #pragma unroll
        for (int p = 0; p < 2; ++p) {
            int m = p * 256 + tid;
            int r = m >> 7, c4 = m & 127;
            float vals[4];
            #pragma unroll
            for (int q = 0; q < 4; ++q) {
                int i = c4 * 4 + q;
                float pos2 = fminf((float)i / res, nlm1f);
                float l2f  = floorf(pos2);
                float fr2  = pos2 - l2f;
                int lo2 = (int)l2f;
                if (lo2 > n_low - 1) lo2 = n_low - 1;
                int hi2 = (lo2 + 1 < n_low) ? (lo2 + 1) : (n_low - 1);
                vals[q] = s_low[r][lo2] * (1.0f - fr2) + s_low[r][hi2] * fr2;
            }
            float4 ov;
            ov.x = vals[0]; ov.y = vals[1]; ov.z = vals[2]; ov.w = vals[3];
            out4[r * 128 + c4] = ov;
        }
    }
}

extern "C" void kernel_launch(void* const* d_in, const int* in_sizes, int n_in,
                              void* d_out, int out_size, void* d_ws, size_t ws_size,
                              hipStream_t stream) {
    const float* x          = (const float*)d_in[0];
    const float* resolution = (const float*)d_in[1];
    const int*   axis       = (const int*)d_in[2];
    const float* gap        = (const float*)d_in[3];
    float* out = (float*)d_out;

    const int n_img = in_sizes[1];   // B*C = 64

    dim3 grid(128, n_img);
    lowres2d_kernel<<<grid, 256, 0, stream>>>(x, resolution, axis, gap, out);
}